// Round 1
// baseline (112.754 us; speedup 1.0000x reference)
//
#include <hip/hip_runtime.h>
#include <hip/hip_bf16.h>

typedef __attribute__((ext_vector_type(4))) float f32x4;
typedef __attribute__((ext_vector_type(8))) short bf16x8;
typedef __attribute__((ext_vector_type(8))) unsigned short ushort8;

#define EPSBN 1e-5f

__device__ __forceinline__ unsigned short f2bf(float f) {
  unsigned int u = __builtin_bit_cast(unsigned int, f);
  u += 0x7fffu + ((u >> 16) & 1u);
  return (unsigned short)(u >> 16);
}

__device__ __forceinline__ void gload_lds16(const unsigned short* g, unsigned short* l) {
  __builtin_amdgcn_global_load_lds(
      (const __attribute__((address_space(1))) void*)g,
      (__attribute__((address_space(3))) void*)l, 16, 0, 0);
}

// ---------- kernel 1: adaptive avg pool to [B,C] ----------
__global__ __launch_bounds__(256) void avg_kernel(const float* __restrict__ x,
                                                  float* __restrict__ avg) {
  int bc = blockIdx.x;                      // b*256 + c
  const float* p = x + (size_t)bc * 1024;
  int tid = threadIdx.x;
  float s = p[tid] + p[tid + 256] + p[tid + 512] + p[tid + 768];
#pragma unroll
  for (int off = 32; off >= 1; off >>= 1) s += __shfl_down(s, off);
  __shared__ float partial[4];
  if ((tid & 63) == 0) partial[tid >> 6] = s;
  __syncthreads();
  if (tid == 0) avg[bc] = (partial[0] + partial[1] + partial[2] + partial[3]) * (1.0f / 1024.0f);
}

// ---------- kernel 2: attention head -> att[B][4] ----------
__global__ __launch_bounds__(256) void att_kernel(
    const float* __restrict__ z, const float* __restrict__ avg,
    const float* __restrict__ w1, const float* __restrict__ gamma,
    const float* __restrict__ beta, const float* __restrict__ mean,
    const float* __restrict__ var, const float* __restrict__ w2,
    float* __restrict__ att) {
  int b = blockIdx.x, t = threadIdx.x;
  __shared__ __align__(16) float a[512];
  __shared__ float h[256];
  a[t] = z[b * 256 + t];
  a[t + 256] = avg[b * 256 + t];
  __syncthreads();
  const float4* wr = reinterpret_cast<const float4*>(w1 + (size_t)t * 512);
  const float4* a4 = reinterpret_cast<const float4*>(a);
  float s = 0.f;
#pragma unroll 4
  for (int j = 0; j < 128; ++j) {
    float4 wv = wr[j], av = a4[j];
    s += wv.x * av.x + wv.y * av.y + wv.z * av.z + wv.w * av.w;
  }
  s = (s - mean[t]) * rsqrtf(var[t] + EPSBN) * gamma[t] + beta[t];
  h[t] = fmaxf(s, 0.f);
  __syncthreads();
  int wv_ = t >> 6, lane = t & 63;
  const float* w2r = w2 + wv_ * 256;
  float p = h[lane] * w2r[lane] + h[lane + 64] * w2r[lane + 64] +
            h[lane + 128] * w2r[lane + 128] + h[lane + 192] * w2r[lane + 192];
#pragma unroll
  for (int off = 32; off >= 1; off >>= 1) p += __shfl_down(p, off);
  if (lane == 0) att[b * 4 + wv_] = 1.0f / (1.0f + expf(-p));
}

// ---------- kernel 3: mix weights -> bf16 agg_w in conv-staging layout ----------
// agg element index: ((((b*9+tap)*8+cc)*4+cblk)*256 + o)*8 + cl ; c = cc*32+cblk*8+cl
__global__ __launch_bounds__(256) void mix_kernel(
    const float* __restrict__ weight, const float* __restrict__ statw,
    const float* __restrict__ att, unsigned short* __restrict__ agg) {
  int tid = blockIdx.x * 256 + threadIdx.x;  // 73728 total = 9*8*4*256
  int o = tid & 255;
  int cblk = (tid >> 8) & 3;
  int cc = (tid >> 10) & 7;
  int tap = tid >> 13;  // 0..8
  int c0 = cc * 32 + cblk * 8;
  float sv[8], wk0[8], wk1[8], wk2[8], wk3[8];
#pragma unroll
  for (int cl = 0; cl < 8; ++cl) {
    int si = (o * 256 + c0 + cl) * 9 + tap;
    sv[cl] = statw[si];
    wk0[cl] = weight[si];
    wk1[cl] = weight[589824 + si];
    wk2[cl] = weight[2 * 589824 + si];
    wk3[cl] = weight[3 * 589824 + si];
  }
  size_t obase = ((size_t)(tap * 8 + cc) * 4 + cblk) * 256 + o;
  for (int b = 0; b < 32; ++b) {
    float a0 = 0.1f * att[b * 4 + 0];
    float a1 = 0.1f * att[b * 4 + 1];
    float a2 = 0.1f * att[b * 4 + 2];
    float a3 = 0.1f * att[b * 4 + 3];
    ushort8 outv;
#pragma unroll
    for (int cl = 0; cl < 8; ++cl) {
      float v = sv[cl] + a0 * wk0[cl] + a1 * wk1[cl] + a2 * wk2[cl] + a3 * wk3[cl];
      outv[cl] = f2bf(v);
    }
    *reinterpret_cast<ushort8*>(agg + ((size_t)b * 73728 + obase) * 8) = outv;
  }
}

// ---------- kernel 4: per-sample implicit-GEMM conv via MFMA ----------
// grid 512 = 32 b * 2 ot * 8 pt ; block 256 = 4 waves (2x2 of 64x64) ; tile 128(o) x 128(hw)
__global__ __launch_bounds__(256, 2) void conv_kernel(
    const float* __restrict__ x, const unsigned short* __restrict__ agg,
    float* __restrict__ out) {
  // XCD-bijective swizzle: 512 blocks -> 64 contiguous logical ids per XCD
  int wgid = (blockIdx.x & 7) * 64 + (blockIdx.x >> 3);
  int pt = wgid & 7;
  int ot = (wgid >> 3) & 1;
  int b = wgid >> 4;
  int h0 = pt * 4;

  __shared__ __align__(16) unsigned short x_lds[4 * 6 * 34 * 8];  // [cblk][r(6)][ci(34)][8c]
  __shared__ __align__(16) unsigned short a_lds[2][4 * 128 * 8];  // dbuf [cblk][o(128)][8c]

  int tid = threadIdx.x;
  int lane = tid & 63, wv = tid >> 6;
  int wave_mo = (wv & 1) * 64;   // o offset of this wave
  int wave_no = (wv >> 1) * 64;  // hw offset of this wave
  int kb = lane >> 4, ln = lane & 15;

  f32x4 acc[4][4];
#pragma unroll
  for (int i = 0; i < 4; ++i)
#pragma unroll
    for (int j = 0; j < 4; ++j) acc[i][j] = (f32x4){0.f, 0.f, 0.f, 0.f};

  const size_t agg_b = (size_t)b * 73728 * 8;  // element base for this b
  int buf = 0;

  for (int cc = 0; cc < 8; ++cc) {
    __syncthreads();  // protect x_lds overwrite from previous c-chunk's readers
    // ---- stage x chunk (channels cc*32..cc*32+31), fp32->bf16, halo + zero pad ----
    for (int s = tid; s < 816; s += 256) {  // 816 = 4*6*34 slots of 8 channels
      int ci = s % 34;
      int t2 = s / 34;
      int r = t2 % 6;
      int cb = t2 / 6;
      int hh = h0 - 1 + r;
      int ww = ci - 1;
      ushort8 v;
      if (hh >= 0 && hh < 32 && ww >= 0 && ww < 32) {
        const float* xp = x + ((size_t)(b * 256 + cc * 32 + cb * 8) * 32 + hh) * 32 + ww;
#pragma unroll
        for (int cl = 0; cl < 8; ++cl) v[cl] = f2bf(xp[cl * 1024]);
      } else {
#pragma unroll
        for (int cl = 0; cl < 8; ++cl) v[cl] = 0;
      }
      *reinterpret_cast<ushort8*>(&x_lds[s * 8]) = v;
    }
    // ---- A(tap) tile staging via global_load_lds; wave wv stages cblk=wv (2x1KB) ----
    auto issueA = [&](int tap, int bsel) {
      const unsigned short* g =
          agg + agg_b + (((size_t)(tap * 8 + cc) * 4 + wv) * 256 + (size_t)ot * 128) * 8;
      unsigned short* l = &a_lds[bsel][wv * 1024];
      gload_lds16(g + lane * 8, l);
      gload_lds16(g + (64 + lane) * 8, l + 512);
    };
    issueA(0, buf);
#pragma unroll
    for (int tap = 0; tap < 9; ++tap) {
      __syncthreads();  // drains vmcnt (A arrived) + lgkm (x writes / prev frag reads)
      if (tap < 8) issueA(tap + 1, buf ^ 1);  // prefetch next tap's A into other buffer
      int dh = tap / 3, dw = tap % 3;
      bf16x8 af[4], bfr[4];
      const unsigned short* ab = &a_lds[buf][kb * 1024];
#pragma unroll
      for (int ai = 0; ai < 4; ++ai)
        af[ai] = *reinterpret_cast<const bf16x8*>(ab + (wave_mo + ai * 16 + ln) * 8);
#pragma unroll
      for (int bj = 0; bj < 4; ++bj) {
        int p = wave_no + bj * 16 + ln;
        int rr = (p >> 5) + dh;
        int wc = (p & 31) + dw;
        bfr[bj] = *reinterpret_cast<const bf16x8*>(&x_lds[((kb * 6 + rr) * 34 + wc) * 8]);
      }
#pragma unroll
      for (int ai = 0; ai < 4; ++ai)
#pragma unroll
        for (int bj = 0; bj < 4; ++bj)
          acc[ai][bj] =
              __builtin_amdgcn_mfma_f32_16x16x32_bf16(af[ai], bfr[bj], acc[ai][bj], 0, 0, 0);
      buf ^= 1;
    }
  }
  // ---- epilogue: C/D layout col=lane&15 (hw), row=(lane>>4)*4+v (o) ----
  size_t ob = ((size_t)b * 256 + ot * 128 + wave_mo) * 1024 + (size_t)pt * 128 + wave_no;
#pragma unroll
  for (int ai = 0; ai < 4; ++ai)
#pragma unroll
    for (int bj = 0; bj < 4; ++bj) {
#pragma unroll
      for (int v = 0; v < 4; ++v) {
        int oo = ai * 16 + (lane >> 4) * 4 + v;
        out[ob + (size_t)oo * 1024 + bj * 16 + ln] = acc[ai][bj][v];
      }
    }
}

extern "C" void kernel_launch(void* const* d_in, const int* in_sizes, int n_in,
                              void* d_out, int out_size, void* d_ws, size_t ws_size,
                              hipStream_t stream) {
  const float* x = (const float*)d_in[0];
  const float* z = (const float*)d_in[1];
  const float* w1 = (const float*)d_in[2];
  const float* gamma = (const float*)d_in[3];
  const float* beta = (const float*)d_in[4];
  const float* mean = (const float*)d_in[5];
  const float* var = (const float*)d_in[6];
  const float* w2 = (const float*)d_in[7];
  const float* weight = (const float*)d_in[8];
  const float* statw = (const float*)d_in[9];
  float* out = (float*)d_out;

  float* att = (float*)d_ws;                                      // 512 B
  float* avg = (float*)((char*)d_ws + 1024);                      // 32 KB
  unsigned short* agg = (unsigned short*)((char*)d_ws + 65536);   // ~36 MB bf16

  avg_kernel<<<8192, 256, 0, stream>>>(x, avg);
  att_kernel<<<32, 256, 0, stream>>>(z, avg, w1, gamma, beta, mean, var, w2, att);
  mix_kernel<<<288, 256, 0, stream>>>(weight, statw, att, agg);
  conv_kernel<<<512, 256, 0, stream>>>(x, agg, out);
}